// Round 1
// baseline (1256.457 us; speedup 1.0000x reference)
//
#include <hip/hip_runtime.h>

// Problem constants (B=4, L=4096, D=2048, DF=4*D=8192, k=L/2=2048)
#define BB 4
#define LL 4096
#define DD 2048
#define DFF 8192
#define KSEL 2048
#define MROWS (BB * KSEL)   // 8192 selected rows total

typedef __bf16 bf16x8 __attribute__((ext_vector_type(8)));
typedef float f32x4 __attribute__((ext_vector_type(4)));
typedef unsigned short u16x8 __attribute__((ext_vector_type(8)));

__device__ __forceinline__ unsigned short f2bf(float f) {
    union { float f; unsigned int u; } v; v.f = f;
    unsigned int u = v.u;
    unsigned int r = u + 0x7fffu + ((u >> 16) & 1u);   // RNE
    return (unsigned short)(r >> 16);
}

__device__ __forceinline__ void gl2lds16(const void* g, void* l) {
    __builtin_amdgcn_global_load_lds(
        (const __attribute__((address_space(1))) void*)g,
        (__attribute__((address_space(3))) void*)l,
        16, 0, 0);
}

// ---------------------------------------------------------------------------
// Router: scores[b*L + l] = dot(x[b,l,:], w_r) + b_r, double accumulation so
// the ordering matches an fp64 reference exactly (top-k membership safety).
// One wave per token; 4 tokens per 256-thread block.
// ---------------------------------------------------------------------------
__global__ __launch_bounds__(256) void router_kernel(
    const float* __restrict__ x, const float* __restrict__ wr,
    const float* __restrict__ br, float* __restrict__ scores)
{
    const int lane = threadIdx.x & 63;
    const int wave = threadIdx.x >> 6;
    const int tok = blockIdx.x * 4 + wave;         // [0, B*L)
    const float* row = x + (long)tok * DD;
    double acc = 0.0;
#pragma unroll
    for (int it = 0; it < 8; ++it) {
        const int off = it * 256 + lane * 4;
        float4 xv = *(const float4*)(row + off);
        float4 wv = *(const float4*)(wr + off);
        acc += (double)xv.x * wv.x + (double)xv.y * wv.y
             + (double)xv.z * wv.z + (double)xv.w * wv.w;
    }
#pragma unroll
    for (int o = 32; o > 0; o >>= 1) acc += __shfl_down(acc, o);
    if (lane == 0) scores[tok] = (float)(acc + (double)br[0]);
}

// ---------------------------------------------------------------------------
// Exact top-k membership by full rank count (tie-break: lower index wins,
// matching jax.lax.top_k). Selected token t of batch b gets slot rank in
// idx[b*KSEL + rank]; ranks of selected tokens are a permutation of [0,k).
// ---------------------------------------------------------------------------
__global__ __launch_bounds__(256) void rank_select_kernel(
    const float* __restrict__ scores, int* __restrict__ idxout)
{
    __shared__ float s[LL];
    const int b = blockIdx.y;
    const float* sb = scores + b * LL;
    for (int i = threadIdx.x; i < LL; i += 256) s[i] = sb[i];
    __syncthreads();
    const int t = blockIdx.x * 256 + threadIdx.x;
    const float my = s[t];
    int rank = 0;
    for (int j = 0; j < LL; ++j) {
        float sj = s[j];
        rank += (sj > my) || (sj == my && j < t);
    }
    if (rank < KSEL) idxout[(b << 11) + rank] = t;
}

// ---------------------------------------------------------------------------
// Convert+transpose fp32 [KR][NC] -> bf16 [NC][KR] (B^T layout for GEMM).
// ---------------------------------------------------------------------------
__global__ __launch_bounds__(256) void conv_transpose_kernel(
    const float* __restrict__ W, unsigned short* __restrict__ Wt,
    int KR, int NC)
{
    __shared__ float tile[32][33];
    const int n0 = blockIdx.x * 32;
    const int k0 = blockIdx.y * 32;
    const int xx = threadIdx.x;     // 0..31
    const int yy = threadIdx.y;     // 0..7
#pragma unroll
    for (int r = 0; r < 32; r += 8)
        tile[yy + r][xx] = W[(long)(k0 + yy + r) * NC + n0 + xx];
    __syncthreads();
#pragma unroll
    for (int r = 0; r < 32; r += 8)
        Wt[(long)(n0 + yy + r) * KR + k0 + xx] = f2bf(tile[xx][yy + r]);
}

// ---------------------------------------------------------------------------
// Gather selected rows of x and convert to bf16: xsel[m,:] = bf16(x[b, tok, :])
// ---------------------------------------------------------------------------
__global__ __launch_bounds__(256) void gather_rows_kernel(
    const float* __restrict__ x, const int* __restrict__ idx,
    unsigned short* __restrict__ xsel)
{
    const int m = blockIdx.x;
    const int b = m >> 11;
    const int tok = idx[m];
    const float* src = x + ((long)b * LL + tok) * DD;
    unsigned short* dst = xsel + (long)m * DD;
    const int c = threadIdx.x * 8;
    float4 v0 = *(const float4*)(src + c);
    float4 v1 = *(const float4*)(src + c + 4);
    u16x8 o;
    o[0] = f2bf(v0.x); o[1] = f2bf(v0.y); o[2] = f2bf(v0.z); o[3] = f2bf(v0.w);
    o[4] = f2bf(v1.x); o[5] = f2bf(v1.y); o[6] = f2bf(v1.z); o[7] = f2bf(v1.w);
    *(u16x8*)(dst + c) = o;
}

// ---------------------------------------------------------------------------
// m97-structure bf16 GEMM: C[M,N] = A[M,K] * Bt[N,K]^T (+bias, +epilogue).
// 128x128 tile, BK=32, 4 waves of 64x64 (4x4 MFMA 16x16x32 tiles).
// MODE 0: store bf16(gelu(v + bias)) into H (row stride N)
// MODE 1: scatter fp32 (v + bias) into Out[b*L + idx[b,r], :] (D cols)
// ---------------------------------------------------------------------------
template <int MODE>
__global__ __launch_bounds__(256) void gemm_bt_kernel(
    const unsigned short* __restrict__ A,
    const unsigned short* __restrict__ Bt,
    const float* __restrict__ bias,
    unsigned short* __restrict__ H,
    const int* __restrict__ idx,
    float* __restrict__ Out,
    int K, int N)
{
    __shared__ unsigned short As[128 * 32];
    __shared__ unsigned short Bs[128 * 32];
    const int tid = threadIdx.x;
    const int lane = tid & 63;
    const int wave = tid >> 6;
    const int wm = wave >> 1, wn = wave & 1;
    const long m0 = (long)blockIdx.y * 128;
    const long n0 = (long)blockIdx.x * 128;

    // staging: 512 16B-chunks per tile; wave w stages chunks [w*128, w*128+128)
    const int c0 = wave * 128 + lane;
    const int c1 = c0 + 64;
    const unsigned short* gA0 = A + (m0 + (c0 >> 2)) * K + (c0 & 3) * 8;
    const unsigned short* gA1 = A + (m0 + (c1 >> 2)) * K + (c1 & 3) * 8;
    const unsigned short* gB0 = Bt + (n0 + (c0 >> 2)) * K + (c0 & 3) * 8;
    const unsigned short* gB1 = Bt + (n0 + (c1 >> 2)) * K + (c1 & 3) * 8;
    unsigned short* lA0 = As + wave * 1024;
    unsigned short* lA1 = As + wave * 1024 + 512;
    unsigned short* lB0 = Bs + wave * 1024;
    unsigned short* lB1 = Bs + wave * 1024 + 512;

    f32x4 acc[4][4];
#pragma unroll
    for (int i = 0; i < 4; ++i)
#pragma unroll
        for (int j = 0; j < 4; ++j) {
            f32x4 z = {0.f, 0.f, 0.f, 0.f};
            acc[i][j] = z;
        }

    const int arow = wm * 64 + (lane & 15);
    const int brow = wn * 64 + (lane & 15);
    const int qk = (lane >> 4) * 8;

    for (int kt = 0; kt < K; kt += 32) {
        gl2lds16(gA0 + kt, lA0);
        gl2lds16(gA1 + kt, lA1);
        gl2lds16(gB0 + kt, lB0);
        gl2lds16(gB1 + kt, lB1);
        __syncthreads();   // drains vmcnt -> LDS deposits visible
        bf16x8 af[4], bfm[4];
#pragma unroll
        for (int i = 0; i < 4; ++i)
            af[i] = *(const bf16x8*)&As[(arow + i * 16) * 32 + qk];
#pragma unroll
        for (int j = 0; j < 4; ++j)
            bfm[j] = *(const bf16x8*)&Bs[(brow + j * 16) * 32 + qk];
#pragma unroll
        for (int i = 0; i < 4; ++i)
#pragma unroll
            for (int j = 0; j < 4; ++j)
                acc[i][j] = __builtin_amdgcn_mfma_f32_16x16x32_bf16(
                    af[i], bfm[j], acc[i][j], 0, 0, 0);
        __syncthreads();   // all waves done reading before next stage
    }

    // Epilogue. C/D layout: col = lane&15, row = (lane>>4)*4 + reg.
    const int colbase = (int)n0 + wn * 64 + (lane & 15);
    const long rowbase = m0 + wm * 64 + ((lane >> 4) << 2);

    if constexpr (MODE == 0) {
#pragma unroll
        for (int i = 0; i < 4; ++i) {
#pragma unroll
            for (int j = 0; j < 4; ++j) {
                const int col = colbase + j * 16;
                const float bv = bias[col];
#pragma unroll
                for (int r = 0; r < 4; ++r) {
                    const long row = rowbase + i * 16 + r;
                    float v = acc[i][j][r] + bv;
                    float t = 0.7978845608028654f * (v + 0.044715f * v * v * v);
                    float g = 0.5f * v * (1.0f + tanhf(t));
                    H[row * N + col] = f2bf(g);
                }
            }
        }
    } else {
        long obase[4][4];
#pragma unroll
        for (int i = 0; i < 4; ++i)
#pragma unroll
            for (int r = 0; r < 4; ++r) {
                const int row = (int)(rowbase + i * 16 + r);
                const int b = row >> 11;
                const int rr = row & (KSEL - 1);
                const int tok = idx[(b << 11) + rr];
                obase[i][r] = ((long)(b * LL + tok)) * DD;
            }
#pragma unroll
        for (int j = 0; j < 4; ++j) {
            const int col = colbase + j * 16;
            const float bv = bias[col];
#pragma unroll
            for (int i = 0; i < 4; ++i)
#pragma unroll
                for (int r = 0; r < 4; ++r)
                    Out[obase[i][r] + col] = acc[i][j][r] + bv;
        }
    }
}

extern "C" void kernel_launch(void* const* d_in, const int* in_sizes, int n_in,
                              void* d_out, int out_size, void* d_ws, size_t ws_size,
                              hipStream_t stream)
{
    const float* x  = (const float*)d_in[0];   // [B,L,D]
    const float* wr = (const float*)d_in[1];   // [D]
    const float* br = (const float*)d_in[2];   // scalar
    const float* w1 = (const float*)d_in[3];   // [D,DF]
    const float* b1 = (const float*)d_in[4];   // [DF]
    const float* w2 = (const float*)d_in[5];   // [DF,D]
    const float* b2 = (const float*)d_in[6];   // [D]
    float* out = (float*)d_out;

    // Workspace carve-up (~234 MB total)
    char* ws = (char*)d_ws;
    float* scores = (float*)ws;              ws += (long)BB * LL * 4;          // 64 KB
    int* idx = (int*)ws;                     ws += (long)BB * KSEL * 4;        // 32 KB
    unsigned short* xsel = (unsigned short*)ws; ws += (long)MROWS * DD * 2;    // 32 MB
    unsigned short* w1t  = (unsigned short*)ws; ws += (long)DFF * DD * 2;      // 32 MB
    unsigned short* w2t  = (unsigned short*)ws; ws += (long)DD * DFF * 2;      // 32 MB
    unsigned short* h    = (unsigned short*)ws; ws += (long)MROWS * DFF * 2;   // 128 MB

    // Zero output (unselected tokens stay 0); capture-safe async memset.
    hipMemsetAsync(d_out, 0, (size_t)out_size * sizeof(float), stream);

    // 1) router scores (double accum for exact top-k membership)
    router_kernel<<<(BB * LL) / 4, 256, 0, stream>>>(x, wr, br, scores);
    // 2) top-k membership + compaction via rank counting
    rank_select_kernel<<<dim3(LL / 256, BB), 256, 0, stream>>>(scores, idx);
    // 3) weights -> bf16 transposed (B^T layout for the GEMMs)
    conv_transpose_kernel<<<dim3(DFF / 32, DD / 32), dim3(32, 8), 0, stream>>>(
        w1, w1t, DD, DFF);
    conv_transpose_kernel<<<dim3(DD / 32, DFF / 32), dim3(32, 8), 0, stream>>>(
        w2, w2t, DFF, DD);
    // 4) gather selected rows, convert to bf16
    gather_rows_kernel<<<MROWS, 256, 0, stream>>>(x, idx, xsel);
    // 5) h = bf16(gelu(xsel @ w1 + b1))   [8192 x 8192]
    gemm_bt_kernel<0><<<dim3(DFF / 128, MROWS / 128), 256, 0, stream>>>(
        xsel, w1t, b1, h, nullptr, nullptr, DD, DFF);
    // 6) out[b, idx, :] = h @ w2 + b2 (scattered)
    gemm_bt_kernel<1><<<dim3(DD / 128, MROWS / 128), 256, 0, stream>>>(
        h, w2t, b2, nullptr, idx, out, DFF, DD);
}

// Round 2
// 1055.503 us; speedup vs baseline: 1.1904x; 1.1904x over previous
//
#include <hip/hip_runtime.h>

// Problem constants (B=4, L=4096, D=2048, DF=4*D=8192, k=L/2=2048)
#define BB 4
#define LL 4096
#define DD 2048
#define DFF 8192
#define KSEL 2048
#define MROWS (BB * KSEL)   // 8192 selected rows total

typedef __bf16 bf16x8 __attribute__((ext_vector_type(8)));
typedef float f32x4 __attribute__((ext_vector_type(4)));
typedef unsigned short u16x8 __attribute__((ext_vector_type(8)));

__device__ __forceinline__ unsigned short f2bf(float f) {
    union { float f; unsigned int u; } v; v.f = f;
    unsigned int u = v.u;
    unsigned int r = u + 0x7fffu + ((u >> 16) & 1u);   // RNE
    return (unsigned short)(r >> 16);
}

__device__ __forceinline__ void gl2lds16(const void* g, void* l) {
    __builtin_amdgcn_global_load_lds(
        (const __attribute__((address_space(1))) void*)g,
        (__attribute__((address_space(3))) void*)l,
        16, 0, 0);
}

// ---------------------------------------------------------------------------
// Router: scores[b*L + l] = dot(x[b,l,:], w_r) + b_r, double accumulation so
// the ordering matches the fp64 numpy reference exactly (top-k membership).
// ---------------------------------------------------------------------------
__global__ __launch_bounds__(256) void router_kernel(
    const float* __restrict__ x, const float* __restrict__ wr,
    const float* __restrict__ br, float* __restrict__ scores)
{
    const int lane = threadIdx.x & 63;
    const int wave = threadIdx.x >> 6;
    const int tok = blockIdx.x * 4 + wave;         // [0, B*L)
    const float* row = x + (long)tok * DD;
    double acc = 0.0;
#pragma unroll
    for (int it = 0; it < 8; ++it) {
        const int off = it * 256 + lane * 4;
        float4 xv = *(const float4*)(row + off);
        float4 wv = *(const float4*)(wr + off);
        acc += (double)xv.x * wv.x + (double)xv.y * wv.y
             + (double)xv.z * wv.z + (double)xv.w * wv.w;
    }
#pragma unroll
    for (int o = 32; o > 0; o >>= 1) acc += __shfl_down(acc, o);
    if (lane == 0) scores[tok] = (float)(acc + (double)br[0]);
}

// ---------------------------------------------------------------------------
// Exact top-k membership by full rank count (tie-break: lower index wins,
// matching jax.lax.top_k). Selected token t of batch b -> slot idx[b*K+rank].
// ---------------------------------------------------------------------------
__global__ __launch_bounds__(256) void rank_select_kernel(
    const float* __restrict__ scores, int* __restrict__ idxout)
{
    __shared__ float s[LL];
    const int b = blockIdx.y;
    const float* sb = scores + b * LL;
    for (int i = threadIdx.x; i < LL; i += 256) s[i] = sb[i];
    __syncthreads();
    const int t = blockIdx.x * 256 + threadIdx.x;
    const float my = s[t];
    int rank = 0;
#pragma unroll 16
    for (int j = 0; j < LL; ++j) {
        float sj = s[j];
        rank += (sj > my) || (sj == my && j < t);
    }
    if (rank < KSEL) idxout[(b << 11) + rank] = t;
}

// ---------------------------------------------------------------------------
// Convert+transpose fp32 [KR][NC] -> bf16 [NC][KR], 64x64 tiles, 16B stores.
// ---------------------------------------------------------------------------
__global__ __launch_bounds__(256) void conv_transpose_kernel(
    const float* __restrict__ W, unsigned short* __restrict__ Wt,
    int KR, int NC)
{
    __shared__ unsigned short t[64 * 72];   // [n][k], pad 72 keeps 16B align
    const int n0 = blockIdx.x * 64;
    const int k0 = blockIdx.y * 64;
    const int tid = threadIdx.x;
    const int rk = tid >> 4;                // 0..15
    const int cn = (tid & 15) * 4;          // 0..60
#pragma unroll
    for (int p = 0; p < 4; ++p) {
        const int k = rk + p * 16;
        float4 v = *(const float4*)(W + (long)(k0 + k) * NC + n0 + cn);
        t[(cn + 0) * 72 + k] = f2bf(v.x);
        t[(cn + 1) * 72 + k] = f2bf(v.y);
        t[(cn + 2) * 72 + k] = f2bf(v.z);
        t[(cn + 3) * 72 + k] = f2bf(v.w);
    }
    __syncthreads();
    const int rn = tid >> 3;                // 0..31
    const int ck = (tid & 7) * 8;           // 0..56
#pragma unroll
    for (int p = 0; p < 2; ++p) {
        const int n = rn + p * 32;
        u16x8 o = *(const u16x8*)&t[n * 72 + ck];
        *(u16x8*)(Wt + (long)(n0 + n) * KR + k0 + ck) = o;
    }
}

// ---------------------------------------------------------------------------
// Gather selected rows of x -> bf16: xsel[m,:] = bf16(x[b, idx[m], :])
// ---------------------------------------------------------------------------
__global__ __launch_bounds__(256) void gather_rows_kernel(
    const float* __restrict__ x, const int* __restrict__ idx,
    unsigned short* __restrict__ xsel)
{
    const int m = blockIdx.x;
    const int b = m >> 11;
    const int tok = idx[m];
    const float* src = x + ((long)b * LL + tok) * DD;
    unsigned short* dst = xsel + (long)m * DD;
    const int c = threadIdx.x * 8;
    float4 v0 = *(const float4*)(src + c);
    float4 v1 = *(const float4*)(src + c + 4);
    u16x8 o;
    o[0] = f2bf(v0.x); o[1] = f2bf(v0.y); o[2] = f2bf(v0.z); o[3] = f2bf(v0.w);
    o[4] = f2bf(v1.x); o[5] = f2bf(v1.y); o[6] = f2bf(v1.z); o[7] = f2bf(v1.w);
    *(u16x8*)(dst + c) = o;
}

// ---------------------------------------------------------------------------
// bf16 GEMM: C[M,N] = A[M,K] * Bt[N,K]^T (+bias, +epilogue).
// 128x128 tile, BK=64 as TWO [128][32] LDS tiles per operand (keeps the
// conflict-free-ish ds_read pattern; a fused [128][64] row would be a
// 16-way bank conflict). GROUP=32 column-major swizzle: A-row readers all
// land on one XCD (pid = const mod 8) -> A-tiles stay in that XCD's L2.
// MODE 0: H[row,col] = bf16(gelu(v + bias))     (row stride N)
// MODE 1: Out[b*L + idx[b,r], col] = v + bias   (fp32 scatter, D cols)
// ---------------------------------------------------------------------------
template <int MODE>
__global__ __launch_bounds__(256, 3) void gemm_bt_kernel(
    const unsigned short* __restrict__ A,
    const unsigned short* __restrict__ Bt,
    const float* __restrict__ bias,
    unsigned short* __restrict__ H,
    const int* __restrict__ idx,
    float* __restrict__ Out,
    int K, int N)
{
    __shared__ unsigned short As[2 * 128 * 32];
    __shared__ unsigned short Bs[2 * 128 * 32];
    const int tid = threadIdx.x;
    const int lane = tid & 63;
    const int wave = tid >> 6;
    const int wm = wave >> 1, wn = wave & 1;

    // grouped swizzle: walk 32 m-rows within each n-column before advancing
    const int npn = gridDim.x;
    const int pid = blockIdx.y * npn + blockIdx.x;
    const int per_grp = 32 * npn;
    const int gid = pid / per_grp;
    const int rem = pid - gid * per_grp;
    const int pm = gid * 32 + (rem & 31);
    const int pn = rem >> 5;
    const long m0 = (long)pm * 128;
    const long n0 = (long)pn * 128;

    // staging: per 32-wide half-tile, 512 16B-chunks; wave w stages
    // chunks [w*128, w*128+128) (lane-contiguous for global_load_lds).
    const int c0 = wave * 128 + lane;
    const int c1 = c0 + 64;
    const unsigned short* gA0 = A + (m0 + (c0 >> 2)) * K + (c0 & 3) * 8;
    const unsigned short* gA1 = A + (m0 + (c1 >> 2)) * K + (c1 & 3) * 8;
    const unsigned short* gB0 = Bt + (n0 + (c0 >> 2)) * K + (c0 & 3) * 8;
    const unsigned short* gB1 = Bt + (n0 + (c1 >> 2)) * K + (c1 & 3) * 8;
    unsigned short* lA0 = As + wave * 1024;
    unsigned short* lA1 = As + wave * 1024 + 512;
    unsigned short* lB0 = Bs + wave * 1024;
    unsigned short* lB1 = Bs + wave * 1024 + 512;

    f32x4 acc[4][4];
#pragma unroll
    for (int i = 0; i < 4; ++i)
#pragma unroll
        for (int j = 0; j < 4; ++j) {
            f32x4 z = {0.f, 0.f, 0.f, 0.f};
            acc[i][j] = z;
        }

    const int arow = wm * 64 + (lane & 15);
    const int brow = wn * 64 + (lane & 15);
    const int qk = (lane >> 4) * 8;

    for (int kt = 0; kt < K; kt += 64) {
#pragma unroll
        for (int h = 0; h < 2; ++h) {
            gl2lds16(gA0 + kt + 32 * h, lA0 + h * 4096);
            gl2lds16(gA1 + kt + 32 * h, lA1 + h * 4096);
            gl2lds16(gB0 + kt + 32 * h, lB0 + h * 4096);
            gl2lds16(gB1 + kt + 32 * h, lB1 + h * 4096);
        }
        __syncthreads();   // drains vmcnt -> LDS deposits visible
#pragma unroll
        for (int s = 0; s < 2; ++s) {
            const unsigned short* as = As + s * 4096;
            const unsigned short* bs = Bs + s * 4096;
            bf16x8 af[4], bfm[4];
#pragma unroll
            for (int i = 0; i < 4; ++i)
                af[i] = *(const bf16x8*)&as[(arow + i * 16) * 32 + qk];
#pragma unroll
            for (int j = 0; j < 4; ++j)
                bfm[j] = *(const bf16x8*)&bs[(brow + j * 16) * 32 + qk];
#pragma unroll
            for (int i = 0; i < 4; ++i)
#pragma unroll
                for (int j = 0; j < 4; ++j)
                    acc[i][j] = __builtin_amdgcn_mfma_f32_16x16x32_bf16(
                        af[i], bfm[j], acc[i][j], 0, 0, 0);
        }
        __syncthreads();   // all waves done reading before next stage
    }

    // Epilogue. C/D layout: col = lane&15, row = (lane>>4)*4 + reg.
    const int colbase = (int)n0 + wn * 64 + (lane & 15);
    const long rowbase = m0 + wm * 64 + ((lane >> 4) << 2);

    if constexpr (MODE == 0) {
#pragma unroll
        for (int i = 0; i < 4; ++i) {
#pragma unroll
            for (int j = 0; j < 4; ++j) {
                const int col = colbase + j * 16;
                const float bv = bias[col];
#pragma unroll
                for (int r = 0; r < 4; ++r) {
                    const long row = rowbase + i * 16 + r;
                    float v = acc[i][j][r] + bv;
                    // tanh-gelu via exp: g = v - v/(1 + e^{1.5957691*u})
                    float u = v + 0.044715f * v * v * v;
                    float e = __expf(1.5957691216057308f * u);
                    float g = v - v * __builtin_amdgcn_rcpf(1.0f + e);
                    H[row * N + col] = f2bf(g);
                }
            }
        }
    } else {
        long obase[4][4];
#pragma unroll
        for (int i = 0; i < 4; ++i)
#pragma unroll
            for (int r = 0; r < 4; ++r) {
                const int row = (int)(rowbase + i * 16 + r);
                const int b = row >> 11;
                const int rr = row & (KSEL - 1);
                const int tok = idx[(b << 11) + rr];
                obase[i][r] = ((long)(b * LL + tok)) * DD;
            }
#pragma unroll
        for (int j = 0; j < 4; ++j) {
            const int col = colbase + j * 16;
            const float bv = bias[col];
#pragma unroll
            for (int i = 0; i < 4; ++i)
#pragma unroll
                for (int r = 0; r < 4; ++r)
                    Out[obase[i][r] + col] = acc[i][j][r] + bv;
        }
    }
}

extern "C" void kernel_launch(void* const* d_in, const int* in_sizes, int n_in,
                              void* d_out, int out_size, void* d_ws, size_t ws_size,
                              hipStream_t stream)
{
    const float* x  = (const float*)d_in[0];   // [B,L,D]
    const float* wr = (const float*)d_in[1];   // [D]
    const float* br = (const float*)d_in[2];   // scalar
    const float* w1 = (const float*)d_in[3];   // [D,DF]
    const float* b1 = (const float*)d_in[4];   // [DF]
    const float* w2 = (const float*)d_in[5];   // [DF,D]
    const float* b2 = (const float*)d_in[6];   // [D]
    float* out = (float*)d_out;

    // Workspace carve-up (~234 MB total)
    char* ws = (char*)d_ws;
    float* scores = (float*)ws;              ws += (long)BB * LL * 4;          // 64 KB
    int* idx = (int*)ws;                     ws += (long)BB * KSEL * 4;        // 32 KB
    unsigned short* xsel = (unsigned short*)ws; ws += (long)MROWS * DD * 2;    // 32 MB
    unsigned short* w1t  = (unsigned short*)ws; ws += (long)DFF * DD * 2;      // 32 MB
    unsigned short* w2t  = (unsigned short*)ws; ws += (long)DD * DFF * 2;      // 32 MB
    unsigned short* h    = (unsigned short*)ws; ws += (long)MROWS * DFF * 2;   // 128 MB

    // Zero output (unselected tokens stay 0); capture-safe async memset.
    hipMemsetAsync(d_out, 0, (size_t)out_size * sizeof(float), stream);

    // 1) router scores (double accum for exact top-k membership)
    router_kernel<<<(BB * LL) / 4, 256, 0, stream>>>(x, wr, br, scores);
    // 2) top-k membership + compaction via rank counting
    rank_select_kernel<<<dim3(LL / 256, BB), 256, 0, stream>>>(scores, idx);
    // 3) weights -> bf16 transposed (B^T layout for the GEMMs)
    conv_transpose_kernel<<<dim3(DFF / 64, DD / 64), 256, 0, stream>>>(
        w1, w1t, DD, DFF);
    conv_transpose_kernel<<<dim3(DD / 64, DFF / 64), 256, 0, stream>>>(
        w2, w2t, DFF, DD);
    // 4) gather selected rows, convert to bf16
    gather_rows_kernel<<<MROWS, 256, 0, stream>>>(x, idx, xsel);
    // 5) h = bf16(gelu(xsel @ w1 + b1))   [8192 x 8192], K=2048
    gemm_bt_kernel<0><<<dim3(DFF / 128, MROWS / 128), 256, 0, stream>>>(
        xsel, w1t, b1, h, nullptr, nullptr, DD, DFF);
    // 6) out[b, idx, :] = h @ w2 + b2 (scattered), K=8192
    gemm_bt_kernel<1><<<dim3(DD / 128, MROWS / 128), 256, 0, stream>>>(
        h, w2t, b2, nullptr, idx, out, DFF, DD);
}

// Round 3
// 1054.139 us; speedup vs baseline: 1.1919x; 1.0013x over previous
//
#include <hip/hip_runtime.h>

// Problem constants (B=4, L=4096, D=2048, DF=4*D=8192, k=L/2=2048)
#define BB 4
#define LL 4096
#define DD 2048
#define DFF 8192
#define KSEL 2048
#define MROWS (BB * KSEL)   // 8192 selected rows total

typedef __bf16 bf16x8 __attribute__((ext_vector_type(8)));
typedef float f32x4 __attribute__((ext_vector_type(4)));
typedef unsigned short u16x8 __attribute__((ext_vector_type(8)));

__device__ __forceinline__ unsigned short f2bf(float f) {
    union { float f; unsigned int u; } v; v.f = f;
    unsigned int u = v.u;
    unsigned int r = u + 0x7fffu + ((u >> 16) & 1u);   // RNE
    return (unsigned short)(r >> 16);
}

__device__ __forceinline__ void gl2lds16(const void* g, void* l) {
    __builtin_amdgcn_global_load_lds(
        (const __attribute__((address_space(1))) void*)g,
        (__attribute__((address_space(3))) void*)l,
        16, 0, 0);
}

// ---------------------------------------------------------------------------
// Router + bf16 conversion of ALL rows (fused; x is read once).
// scores[tok] = dot(x[tok,:], w_r) + b_r in double (exact top-k membership vs
// the fp64 numpy reference); xbf[tok,:] = bf16(x[tok,:]).
// One wave per token; 4 tokens per block.
// ---------------------------------------------------------------------------
__global__ __launch_bounds__(256) void router_conv_kernel(
    const float* __restrict__ x, const float* __restrict__ wr,
    const float* __restrict__ br, float* __restrict__ scores,
    unsigned short* __restrict__ xbf)
{
    const int lane = threadIdx.x & 63;
    const int wave = threadIdx.x >> 6;
    const int tok = blockIdx.x * 4 + wave;         // [0, B*L)
    const float* row = x + (long)tok * DD;
    unsigned short* orow = xbf + (long)tok * DD;
    double acc = 0.0;
#pragma unroll
    for (int it = 0; it < 4; ++it) {
        const int off = it * 512 + lane * 8;
        float4 xv = *(const float4*)(row + off);
        float4 xw = *(const float4*)(row + off + 4);
        float4 wv = *(const float4*)(wr + off);
        float4 ww = *(const float4*)(wr + off + 4);
        acc += (double)xv.x * wv.x + (double)xv.y * wv.y
             + (double)xv.z * wv.z + (double)xv.w * wv.w;
        acc += (double)xw.x * ww.x + (double)xw.y * ww.y
             + (double)xw.z * ww.z + (double)xw.w * ww.w;
        u16x8 o;
        o[0] = f2bf(xv.x); o[1] = f2bf(xv.y); o[2] = f2bf(xv.z); o[3] = f2bf(xv.w);
        o[4] = f2bf(xw.x); o[5] = f2bf(xw.y); o[6] = f2bf(xw.z); o[7] = f2bf(xw.w);
        *(u16x8*)(orow + off) = o;
    }
#pragma unroll
    for (int o = 32; o > 0; o >>= 1) acc += __shfl_down(acc, o);
    if (lane == 0) scores[tok] = (float)(acc + (double)br[0]);
}

// ---------------------------------------------------------------------------
// Exact top-k membership by full rank count (tie-break: lower index wins,
// matching jax.lax.top_k). rank<K -> idx[b*K+rank]=t (selected, compacted);
// rank>=K -> zidx[b*(L-K) + rank-K]=t (rows to zero in the output).
// ---------------------------------------------------------------------------
__global__ __launch_bounds__(256) void rank_select_kernel(
    const float* __restrict__ scores, int* __restrict__ idxout,
    int* __restrict__ zidxout)
{
    __shared__ float s[LL];
    const int b = blockIdx.y;
    const float* sb = scores + b * LL;
    for (int i = threadIdx.x; i < LL; i += 256) s[i] = sb[i];
    __syncthreads();
    const int t = blockIdx.x * 256 + threadIdx.x;
    const float my = s[t];
    int rank = 0;
#pragma unroll 16
    for (int j = 0; j < LL; ++j) {
        float sj = s[j];
        rank += (sj > my) || (sj == my && j < t);
    }
    if (rank < KSEL) idxout[(b << 11) + rank] = t;
    else             zidxout[(b << 11) + rank - KSEL] = t;
}

// ---------------------------------------------------------------------------
// Zero the output rows of unselected tokens (replaces full-out memset).
// One block per unselected row (8 KB fp32).
// ---------------------------------------------------------------------------
__global__ __launch_bounds__(256) void zero_rows_kernel(
    const int* __restrict__ zidx, float* __restrict__ Out)
{
    const int m = blockIdx.x;
    const int b = m >> 11;
    const int tok = zidx[m];
    float* dst = Out + ((long)b * LL + tok) * DD;
    const int c = threadIdx.x * 8;
    float4 z = {0.f, 0.f, 0.f, 0.f};
    *(float4*)(dst + c) = z;
    *(float4*)(dst + c + 4) = z;
}

// ---------------------------------------------------------------------------
// Convert+transpose BOTH weights in one launch.
// fp32 [KR][NC] -> bf16 [NC][KR], 64x64 tiles, 16B stores.
// blocks [0, 4096): w1 (KR=DD, NC=DFF); [4096, 8192): w2 (KR=DFF, NC=DD).
// ---------------------------------------------------------------------------
__global__ __launch_bounds__(256) void conv_transpose2_kernel(
    const float* __restrict__ W1, unsigned short* __restrict__ W1t,
    const float* __restrict__ W2, unsigned short* __restrict__ W2t)
{
    __shared__ unsigned short t[64 * 72];
    int bid = blockIdx.x;
    const float* W; unsigned short* Wt; int KR, NC, bx, by;
    if (bid < 4096) { W = W1; Wt = W1t; KR = DD; NC = DFF; bx = bid & 127; by = bid >> 7; }
    else { bid -= 4096; W = W2; Wt = W2t; KR = DFF; NC = DD; bx = bid & 31; by = bid >> 5; }
    const int n0 = bx * 64;
    const int k0 = by * 64;
    const int tid = threadIdx.x;
    const int rk = tid >> 4;                // 0..15
    const int cn = (tid & 15) * 4;          // 0..60
#pragma unroll
    for (int p = 0; p < 4; ++p) {
        const int k = rk + p * 16;
        float4 v = *(const float4*)(W + (long)(k0 + k) * NC + n0 + cn);
        t[(cn + 0) * 72 + k] = f2bf(v.x);
        t[(cn + 1) * 72 + k] = f2bf(v.y);
        t[(cn + 2) * 72 + k] = f2bf(v.z);
        t[(cn + 3) * 72 + k] = f2bf(v.w);
    }
    __syncthreads();
    const int rn = tid >> 3;                // 0..31
    const int ck = (tid & 7) * 8;           // 0..56
#pragma unroll
    for (int p = 0; p < 2; ++p) {
        const int n = rn + p * 32;
        u16x8 o = *(const u16x8*)&t[n * 72 + ck];
        *(u16x8*)(Wt + (long)(n0 + n) * KR + k0 + ck) = o;
    }
}

// ---------------------------------------------------------------------------
// bf16 GEMM: C[M,N] = A[M,K] * Bt[N,K]^T (+bias, +epilogue).
// 128x128 tile, BK=64 as TWO [128][32] LDS tiles per operand. GROUP=32
// column-major block swizzle for L2 locality. 4 blocks/CU (128 KB LDS).
// IND=1: A row m is xbf row idx[m] (fused gather; A stride = K = DD).
// MODE 0: H[row,col] = bf16(gelu(v + bias))     (row stride N)
// MODE 1: Out[b*L + idx[b,r], col] = v + bias   (fp32 scatter, D cols)
// ---------------------------------------------------------------------------
template <int MODE, int IND>
__global__ __launch_bounds__(256, 4) void gemm_bt_kernel(
    const unsigned short* __restrict__ A,
    const unsigned short* __restrict__ Bt,
    const float* __restrict__ bias,
    unsigned short* __restrict__ H,
    const int* __restrict__ idx,
    float* __restrict__ Out,
    int K, int N)
{
    __shared__ unsigned short As[2 * 128 * 32];
    __shared__ unsigned short Bs[2 * 128 * 32];
    const int tid = threadIdx.x;
    const int lane = tid & 63;
    const int wave = tid >> 6;
    const int wm = wave >> 1, wn = wave & 1;

    // grouped swizzle: walk 32 m-rows within each n-column before advancing
    const int npn = gridDim.x;
    const int pid = blockIdx.y * npn + blockIdx.x;
    const int per_grp = 32 * npn;
    const int gid = pid / per_grp;
    const int rem = pid - gid * per_grp;
    const int pm = gid * 32 + (rem & 31);
    const int pn = rem >> 5;
    const long m0 = (long)pm * 128;
    const long n0 = (long)pn * 128;

    // staging: per 32-wide half-tile, 512 16B-chunks; wave w stages
    // chunks [w*128, w*128+128) (lane-contiguous for global_load_lds).
    const int c0 = wave * 128 + lane;
    const int c1 = c0 + 64;
    long ar0, ar1;
    if constexpr (IND) {
        const int r0 = (int)m0 + (c0 >> 2), r1 = (int)m0 + (c1 >> 2);
        ar0 = (long)(r0 >> 11) * LL + idx[r0];
        ar1 = (long)(r1 >> 11) * LL + idx[r1];
    } else {
        ar0 = m0 + (c0 >> 2);
        ar1 = m0 + (c1 >> 2);
    }
    const unsigned short* gA0 = A + ar0 * K + (c0 & 3) * 8;
    const unsigned short* gA1 = A + ar1 * K + (c1 & 3) * 8;
    const unsigned short* gB0 = Bt + (n0 + (c0 >> 2)) * K + (c0 & 3) * 8;
    const unsigned short* gB1 = Bt + (n0 + (c1 >> 2)) * K + (c1 & 3) * 8;
    unsigned short* lA0 = As + wave * 1024;
    unsigned short* lA1 = As + wave * 1024 + 512;
    unsigned short* lB0 = Bs + wave * 1024;
    unsigned short* lB1 = Bs + wave * 1024 + 512;

    f32x4 acc[4][4];
#pragma unroll
    for (int i = 0; i < 4; ++i)
#pragma unroll
        for (int j = 0; j < 4; ++j) {
            f32x4 z = {0.f, 0.f, 0.f, 0.f};
            acc[i][j] = z;
        }

    const int arow = wm * 64 + (lane & 15);
    const int brow = wn * 64 + (lane & 15);
    const int qk = (lane >> 4) * 8;

    for (int kt = 0; kt < K; kt += 64) {
#pragma unroll
        for (int h = 0; h < 2; ++h) {
            gl2lds16(gA0 + kt + 32 * h, lA0 + h * 4096);
            gl2lds16(gA1 + kt + 32 * h, lA1 + h * 4096);
            gl2lds16(gB0 + kt + 32 * h, lB0 + h * 4096);
            gl2lds16(gB1 + kt + 32 * h, lB1 + h * 4096);
        }
        __syncthreads();   // drains vmcnt -> LDS deposits visible
#pragma unroll
        for (int s = 0; s < 2; ++s) {
            const unsigned short* as = As + s * 4096;
            const unsigned short* bs = Bs + s * 4096;
            bf16x8 af[4], bfm[4];
#pragma unroll
            for (int i = 0; i < 4; ++i)
                af[i] = *(const bf16x8*)&as[(arow + i * 16) * 32 + qk];
#pragma unroll
            for (int j = 0; j < 4; ++j)
                bfm[j] = *(const bf16x8*)&bs[(brow + j * 16) * 32 + qk];
#pragma unroll
            for (int i = 0; i < 4; ++i)
#pragma unroll
                for (int j = 0; j < 4; ++j)
                    acc[i][j] = __builtin_amdgcn_mfma_f32_16x16x32_bf16(
                        af[i], bfm[j], acc[i][j], 0, 0, 0);
        }
        __syncthreads();   // all waves done reading before next stage
    }

    // Epilogue. C/D layout: col = lane&15, row = (lane>>4)*4 + reg.
    const int colbase = (int)n0 + wn * 64 + (lane & 15);
    const long rowbase = m0 + wm * 64 + ((lane >> 4) << 2);

    if constexpr (MODE == 0) {
#pragma unroll
        for (int i = 0; i < 4; ++i) {
#pragma unroll
            for (int j = 0; j < 4; ++j) {
                const int col = colbase + j * 16;
                const float bv = bias[col];
#pragma unroll
                for (int r = 0; r < 4; ++r) {
                    const long row = rowbase + i * 16 + r;
                    float v = acc[i][j][r] + bv;
                    // tanh-gelu via exp: g = v - v/(1 + e^{1.5957691*u})
                    float u = v + 0.044715f * v * v * v;
                    float e = __expf(1.5957691216057308f * u);
                    float g = v - v * __builtin_amdgcn_rcpf(1.0f + e);
                    H[row * N + col] = f2bf(g);
                }
            }
        }
    } else {
        long obase[4][4];
#pragma unroll
        for (int i = 0; i < 4; ++i)
#pragma unroll
            for (int r = 0; r < 4; ++r) {
                const int row = (int)(rowbase + i * 16 + r);
                const int b = row >> 11;
                const int rr = row & (KSEL - 1);
                const int tok = idx[(b << 11) + rr];
                obase[i][r] = ((long)(b * LL + tok)) * DD;
            }
#pragma unroll
        for (int j = 0; j < 4; ++j) {
            const int col = colbase + j * 16;
            const float bv = bias[col];
#pragma unroll
            for (int i = 0; i < 4; ++i)
#pragma unroll
                for (int r = 0; r < 4; ++r)
                    Out[obase[i][r] + col] = acc[i][j][r] + bv;
        }
    }
}

extern "C" void kernel_launch(void* const* d_in, const int* in_sizes, int n_in,
                              void* d_out, int out_size, void* d_ws, size_t ws_size,
                              hipStream_t stream)
{
    const float* x  = (const float*)d_in[0];   // [B,L,D]
    const float* wr = (const float*)d_in[1];   // [D]
    const float* br = (const float*)d_in[2];   // scalar
    const float* w1 = (const float*)d_in[3];   // [D,DF]
    const float* b1 = (const float*)d_in[4];   // [DF]
    const float* w2 = (const float*)d_in[5];   // [DF,D]
    const float* b2 = (const float*)d_in[6];   // [D]
    float* out = (float*)d_out;

    // Workspace carve-up (~290 MB total)
    char* ws = (char*)d_ws;
    float* scores = (float*)ws;              ws += (long)BB * LL * 4;          // 64 KB
    int* idx  = (int*)ws;                    ws += (long)BB * KSEL * 4;        // 32 KB
    int* zidx = (int*)ws;                    ws += (long)BB * (LL - KSEL) * 4; // 32 KB
    unsigned short* xbf  = (unsigned short*)ws; ws += (long)BB * LL * DD * 2;  // 64 MB
    unsigned short* w1t  = (unsigned short*)ws; ws += (long)DFF * DD * 2;      // 32 MB
    unsigned short* w2t  = (unsigned short*)ws; ws += (long)DD * DFF * 2;      // 32 MB
    unsigned short* h    = (unsigned short*)ws; ws += (long)MROWS * DFF * 2;   // 128 MB

    // 1) router scores (double accum) + bf16 conversion of all of x
    router_conv_kernel<<<(BB * LL) / 4, 256, 0, stream>>>(x, wr, br, scores, xbf);
    // 2) weights -> bf16 transposed (B^T layout), both in one launch
    conv_transpose2_kernel<<<8192, 256, 0, stream>>>(w1, w1t, w2, w2t);
    // 3) top-k membership + compaction (selected and unselected lists)
    rank_select_kernel<<<dim3(LL / 256, BB), 256, 0, stream>>>(scores, idx, zidx);
    // 4) zero only the unselected output rows
    zero_rows_kernel<<<BB * (LL - KSEL), 256, 0, stream>>>(zidx, out);
    // 5) h = bf16(gelu(gather(x)[idx] @ w1 + b1))  [8192 x 8192], K=2048
    gemm_bt_kernel<0, 1><<<dim3(DFF / 128, MROWS / 128), 256, 0, stream>>>(
        xbf, w1t, b1, h, idx, nullptr, DD, DFF);
    // 6) out[b, idx, :] = h @ w2 + b2 (scattered), K=8192
    gemm_bt_kernel<1, 0><<<dim3(DD / 128, MROWS / 128), 256, 0, stream>>>(
        h, w2t, b2, nullptr, idx, out, DFF, DD);
}